// Round 4
// baseline (99.109 us; speedup 1.0000x reference)
//
#include <hip/hip_runtime.h>

typedef __attribute__((ext_vector_type(8))) short bf16x8;
typedef __attribute__((ext_vector_type(4))) float f32x4;
typedef __attribute__((ext_vector_type(8))) unsigned short u16x8;

#define BB 32
#define NN 1024
#define MM 256
#define HH 128

__device__ __forceinline__ unsigned short f2bf(float f) {
  union { float f; unsigned int u; } c; c.f = f;
  unsigned int u = c.u + 0x7fffu + ((c.u >> 16) & 1u);  // RNE
  return (unsigned short)(u >> 16);
}
__device__ __forceinline__ unsigned int pack2(float lo, float hi) {
  return (unsigned int)f2bf(lo) | ((unsigned int)f2bf(hi) << 16);
}

// ---------------- h transpose: h[B][N][M] f32 -> hT[B][M][N] bf16 ----------------
__global__ __launch_bounds__(256)
void k_transpose_h(const float* __restrict__ hg, unsigned short* __restrict__ hTg) {
  __shared__ unsigned short tile[64][65];
  int bid = blockIdx.x;
  int b = bid >> 6;
  int t = bid & 63;
  int k0 = (t >> 2) << 6;
  int m0 = (t & 3) << 6;
  int tt = threadIdx.x;
  {
    int r = tt >> 2;
    int cg = (tt & 3) << 4;
    const float* src = hg + (((size_t)b * NN + k0 + r) * MM + m0 + cg);
#pragma unroll
    for (int i = 0; i < 4; ++i) {
      float4 v = reinterpret_cast<const float4*>(src)[i];
      tile[r][cg + i * 4 + 0] = f2bf(v.x);
      tile[r][cg + i * 4 + 1] = f2bf(v.y);
      tile[r][cg + i * 4 + 2] = f2bf(v.z);
      tile[r][cg + i * 4 + 3] = f2bf(v.w);
    }
  }
  __syncthreads();
  {
    int mr = tt >> 2;
    int kc = (tt & 3) << 4;
    alignas(16) unsigned short tmp[16];
#pragma unroll
    for (int i = 0; i < 16; ++i) tmp[i] = tile[kc + i][mr];
    unsigned short* dst = hTg + (((size_t)b * MM + m0 + mr) * NN + k0 + kc);
    *reinterpret_cast<u16x8*>(dst)     = *reinterpret_cast<u16x8*>(tmp);
    *reinterpret_cast<u16x8*>(dst + 8) = *reinterpret_cast<u16x8*>(tmp + 8);
  }
}

// ------------- W transposes -------------
__global__ __launch_bounds__(256)
void k_transpose_w(const float* __restrict__ W1, const float* __restrict__ W2,
                   unsigned short* __restrict__ W1T, unsigned short* __restrict__ W2T) {
  int idx = blockIdx.x * 256 + threadIdx.x;
  if (idx < MM * HH) {
    int hc = idx >> 8;
    int m  = idx & 255;
    W1T[idx] = f2bf(W1[m * HH + hc]);
  } else {
    int j = idx - MM * HH;
    int m  = j >> 7;
    int hd = j & 127;
    W2T[j] = f2bf(W2[hd * MM + m]);
  }
}

// ---------------- fused main ----------------
// 1024 blocks x 256 threads (4 waves col-split). Block tile: 32 rows x 256 cols.
// LDS 24 KB: A dbuf [0,8K) (2 x 4KB), Kld [8K,24K), Cld reuses [0,8K).
// Phase-1 barriers are lgkm-only (no global->LDS handoff; reg prefetches
// survive the barrier). W1/W2 read directly from L2-hot global (no LDS).
#define ABUF(i) ((i) * 4096)
#define KLD 8192
#define CLD 0

#define PIPE_BARRIER() do { \
  asm volatile("s_waitcnt lgkmcnt(0)" ::: "memory"); \
  __builtin_amdgcn_s_barrier(); } while (0)

__global__ __launch_bounds__(256, 3)
void k_fused(const float* __restrict__ Ag, const float* __restrict__ hg,
             const unsigned short* __restrict__ hTg,
             const unsigned short* __restrict__ W1Tg,
             const unsigned short* __restrict__ W2Tg,
             const float* __restrict__ b1g, const float* __restrict__ b2g,
             float* __restrict__ outg) {
  __shared__ __align__(16) char smem[24576];
  __shared__ float smax[32];

  const int tid  = threadIdx.x;
  const int lane = tid & 63;
  const int wid  = tid >> 6;       // 0..3
  const int l15  = lane & 15;
  const int lg   = lane >> 4;      // 0..3
  const int wcol = wid << 6;       // 0,64,128,192

  const int bid = blockIdx.x;
  const int b   = bid & 31;        // same-batch blocks share bid%8 -> same XCD L2
  const int r0  = (bid >> 5) << 5; // 32 row-blocks of 32

  const float* Ab = Ag + ((size_t)b * NN + r0) * NN;
  const unsigned short* hTb = hTg + (size_t)b * MM * NN;

  f32x4 acc[2][4];
#pragma unroll
  for (int m = 0; m < 2; ++m)
#pragma unroll
    for (int n = 0; n < 4; ++n) acc[m][n] = f32x4{0.f, 0.f, 0.f, 0.f};

  float pmax = -1e30f;
  const int arow = tid >> 3;          // 0..31
  const int acg  = (tid & 7) << 3;    // 8-float chunk
  const float* Asrc = Ab + (size_t)arow * NN + acg;

  float4  ar[4][2];     // 4-deep A prefetch (8 floats each)
  bf16x8  hb[2][2][4];  // 2-deep H prefetch: [buf][kk][n]

#define ISSUEA(R, K0)                                                        \
  do {                                                                       \
    (R)[0] = reinterpret_cast<const float4*>(Asrc + (K0))[0];                \
    (R)[1] = reinterpret_cast<const float4*>(Asrc + (K0))[1];                \
  } while (0)

#define LOADH(H, K0)                                                         \
  do {                                                                       \
    _Pragma("unroll")                                                        \
    for (int kk = 0; kk < 2; ++kk)                                           \
      _Pragma("unroll")                                                      \
      for (int n = 0; n < 4; ++n)                                            \
        (H)[kk][n] = *reinterpret_cast<const bf16x8*>(                       \
            hTb + (size_t)(wcol + (n << 4) + l15) * NN + (K0) + kk * 32 +    \
            (lg << 3));                                                      \
  } while (0)

#define CVTWRA(BASE, R)                                                      \
  do {                                                                       \
    float m0 = fmaxf(fmaxf((R)[0].x, (R)[0].y), fmaxf((R)[0].z, (R)[0].w));  \
    float m1 = fmaxf(fmaxf((R)[1].x, (R)[1].y), fmaxf((R)[1].z, (R)[1].w));  \
    pmax = fmaxf(pmax, fmaxf(m0, m1));                                       \
    unsigned int p0 = pack2((R)[0].x, (R)[0].y), p1 = pack2((R)[0].z, (R)[0].w); \
    unsigned int p2 = pack2((R)[1].x, (R)[1].y), p3 = pack2((R)[1].z, (R)[1].w); \
    *reinterpret_cast<uint4*>(smem + (BASE) + arow * 128 +                   \
                              (((acg << 1)) ^ ((arow & 7) << 4))) =          \
        make_uint4(p0, p1, p2, p3);                                          \
  } while (0)

#define CONS(BASE, H)                                                        \
  do {                                                                       \
    _Pragma("unroll")                                                        \
    for (int kk = 0; kk < 2; ++kk) {                                         \
      bf16x8 af[2];                                                          \
      _Pragma("unroll")                                                      \
      for (int m = 0; m < 2; ++m) {                                          \
        int row = (m << 4) + l15;                                            \
        af[m] = *reinterpret_cast<const bf16x8*>(                            \
            smem + (BASE) + row * 128 +                                      \
            (((kk * 32 + (lg << 3)) * 2) ^ ((row & 7) << 4)));               \
      }                                                                      \
      _Pragma("unroll")                                                      \
      for (int m = 0; m < 2; ++m)                                            \
        _Pragma("unroll")                                                    \
        for (int n = 0; n < 4; ++n)                                          \
          acc[m][n] = __builtin_amdgcn_mfma_f32_16x16x32_bf16(af[m],         \
              (H)[kk][n], acc[m][n], 0, 0, 0);                               \
    }                                                                        \
  } while (0)

  // -------- prologue: A 4-deep, H 2-deep, stage step-0 --------
#pragma unroll
  for (int t = 0; t < 4; ++t) ISSUEA(ar[t], t * 64);
  LOADH(hb[0], 0);
  LOADH(hb[1], 64);
  CVTWRA(ABUF(0), ar[0]);
  PIPE_BARRIER();

  // -------- phase 1: 16 K-steps of 64, one lgkm-barrier per step --------
#pragma unroll
  for (int t = 0; t < 16; ++t) {
    if (t + 4 < 16) ISSUEA(ar[t & 3], (t + 4) * 64);   // A(t+4), used at t+3
    CONS(ABUF(t & 1), hb[t & 1]);                      // consume A(t) x H(t)
    if (t + 1 < 16) CVTWRA(ABUF((t + 1) & 1), ar[(t + 1) & 3]);  // stage A(t+1)
    if (t + 2 < 16) LOADH(hb[t & 1], (t + 2) * 64);    // H(t+2)
    PIPE_BARRIER();
  }

  // -------- row-max finalize (8 staging lanes per row) --------
  {
    float v = pmax;
    v = fmaxf(v, __shfl_xor(v, 1));
    v = fmaxf(v, __shfl_xor(v, 2));
    v = fmaxf(v, __shfl_xor(v, 4));
    if ((tid & 7) == 0) smax[arow] = v;
  }

  // -------- write k tile (/3, bf16) -> Kld [32][512B] XOR --------
  {
    const float inv3 = 1.0f / 3.0f;
#pragma unroll
    for (int m = 0; m < 2; ++m)
#pragma unroll
      for (int n = 0; n < 4; ++n) {
        int col = wcol + (n << 4) + l15;
#pragma unroll
        for (int j = 0; j < 4; ++j) {
          int row = (m << 4) + (lg << 2) + j;
          *reinterpret_cast<unsigned short*>(smem + KLD + row * 512 +
                                             ((col * 2) ^ ((row & 7) << 4))) =
              f2bf(acc[m][n][j] * inv3);
        }
      }
  }
  PIPE_BARRIER();

  // -------- GEMM1: y[32][128] = k @ W1 (W1T frags straight from L2) --------
  f32x4 acc1[2][2];
#pragma unroll
  for (int m = 0; m < 2; ++m)
#pragma unroll
    for (int n = 0; n < 2; ++n) acc1[m][n] = f32x4{0.f, 0.f, 0.f, 0.f};
  const int wcol1 = wid << 5;  // 0,32,64,96
#pragma unroll
  for (int kq = 0; kq < 8; ++kq) {
    bf16x8 af[2], bw[2];
#pragma unroll
    for (int m = 0; m < 2; ++m) {
      int row = (m << 4) + l15;
      af[m] = *reinterpret_cast<const bf16x8*>(smem + KLD + row * 512 +
              (((kq * 32 + (lg << 3)) * 2) ^ ((row & 7) << 4)));
    }
#pragma unroll
    for (int n = 0; n < 2; ++n) {
      int col = wcol1 + (n << 4) + l15;
      bw[n] = *reinterpret_cast<const bf16x8*>(W1Tg + (size_t)col * 256 +
                                               kq * 32 + (lg << 3));
    }
#pragma unroll
    for (int m = 0; m < 2; ++m)
#pragma unroll
      for (int n = 0; n < 2; ++n)
        acc1[m][n] = __builtin_amdgcn_mfma_f32_16x16x32_bf16(af[m], bw[n], acc1[m][n], 0, 0, 0);
  }

  // -------- c = relu(y+b1) -> Cld [32][256B] XOR (disjoint from Kld) --------
  {
#pragma unroll
    for (int n = 0; n < 2; ++n) {
      int col = wcol1 + (n << 4) + l15;
      float bias = b1g[col];
#pragma unroll
      for (int m = 0; m < 2; ++m)
#pragma unroll
        for (int j = 0; j < 4; ++j) {
          int row = (m << 4) + (lg << 2) + j;
          float v = fmaxf(acc1[m][n][j] + bias, 0.f);
          *reinterpret_cast<unsigned short*>(smem + CLD + row * 256 +
                                             ((col * 2) ^ ((row & 7) << 4))) = f2bf(v);
        }
    }
  }
  PIPE_BARRIER();

  // -------- GEMM2: out2[32][256] = c @ W2 (W2T frags from L2) --------
  f32x4 acc2[2][4];
#pragma unroll
  for (int m = 0; m < 2; ++m)
#pragma unroll
    for (int n = 0; n < 4; ++n) acc2[m][n] = f32x4{0.f, 0.f, 0.f, 0.f};
#pragma unroll
  for (int kq = 0; kq < 4; ++kq) {
    bf16x8 af[2], bw[4];
#pragma unroll
    for (int m = 0; m < 2; ++m) {
      int row = (m << 4) + l15;
      af[m] = *reinterpret_cast<const bf16x8*>(smem + CLD + row * 256 +
              (((kq * 32 + (lg << 3)) * 2) ^ ((row & 7) << 4)));
    }
#pragma unroll
    for (int n = 0; n < 4; ++n) {
      int col = wcol + (n << 4) + l15;
      bw[n] = *reinterpret_cast<const bf16x8*>(W2Tg + (size_t)col * 128 +
                                               kq * 32 + (lg << 3));
    }
#pragma unroll
    for (int m = 0; m < 2; ++m)
#pragma unroll
      for (int n = 0; n < 4; ++n)
        acc2[m][n] = __builtin_amdgcn_mfma_f32_16x16x32_bf16(af[m], bw[n], acc2[m][n], 0, 0, 0);
  }

  // -------- epilogue: out = (out2+b2)*mask + h*(1-mask) --------
  {
#pragma unroll
    for (int n = 0; n < 4; ++n) {
      int col = wcol + (n << 4) + l15;
      float b2v = b2g[col];
#pragma unroll
      for (int m = 0; m < 2; ++m)
#pragma unroll
        for (int j = 0; j < 4; ++j) {
          int row = (m << 4) + (lg << 2) + j;
          float kv = acc2[m][n][j] + b2v;
          float mask = smax[row];
          size_t gidx = ((size_t)b * NN + r0 + row) * MM + col;
          float hv = hg[gidx];
          outg[gidx] = kv * mask + hv * (1.f - mask);
        }
    }
  }
#undef CONS
#undef CVTWRA
#undef LOADH
#undef ISSUEA
}

extern "C" void kernel_launch(void* const* d_in, const int* in_sizes, int n_in,
                              void* d_out, int out_size, void* d_ws, size_t ws_size,
                              hipStream_t stream) {
  (void)in_sizes; (void)n_in; (void)out_size; (void)ws_size;
  const float* A  = (const float*)d_in[0];
  const float* h  = (const float*)d_in[1];
  const float* W1 = (const float*)d_in[2];
  const float* b1 = (const float*)d_in[3];
  const float* W2 = (const float*)d_in[4];
  const float* b2 = (const float*)d_in[5];
  float* out = (float*)d_out;

  unsigned short* hT  = (unsigned short*)d_ws;
  unsigned short* W1T = (unsigned short*)((char*)d_ws + (size_t)BB * MM * NN * 2);
  unsigned short* W2T = W1T + MM * HH;

  k_transpose_h<<<BB * 64, 256, 0, stream>>>(h, hT);
  k_transpose_w<<<256, 256, 0, stream>>>(W1, W2, W1T, W2T);
  k_fused<<<BB * 32, 256, 0, stream>>>(A, h, hT, W1T, W2T, b1, b2, out);
}

// Round 5
// 76.443 us; speedup vs baseline: 1.2965x; 1.2965x over previous
//
#include <hip/hip_runtime.h>

typedef __attribute__((ext_vector_type(8))) short bf16x8;
typedef __attribute__((ext_vector_type(4))) float f32x4;
typedef __attribute__((ext_vector_type(8))) unsigned short u16x8;

#define BB 32
#define NN 1024
#define MM 256
#define HH 128

__device__ __forceinline__ unsigned short f2bf(float f) {
  union { float f; unsigned int u; } c; c.f = f;
  unsigned int u = c.u + 0x7fffu + ((c.u >> 16) & 1u);  // RNE
  return (unsigned short)(u >> 16);
}
__device__ __forceinline__ unsigned int pack2(float lo, float hi) {
  return (unsigned int)f2bf(lo) | ((unsigned int)f2bf(hi) << 16);
}

typedef __attribute__((address_space(3))) unsigned int as3_u32;
typedef const __attribute__((address_space(1))) unsigned int as1_u32;
__device__ __forceinline__ void gl_lds16(const void* g, void* l) {
  __builtin_amdgcn_global_load_lds((as1_u32*)g, (as3_u32*)l, 16, 0, 0);
}

// ---------------- h transpose: h[B][N][M] f32 -> hT[B][M][N] bf16 ----------------
__global__ __launch_bounds__(256)
void k_transpose_h(const float* __restrict__ hg, unsigned short* __restrict__ hTg) {
  __shared__ unsigned short tile[64][65];
  int bid = blockIdx.x;
  int b = bid >> 6;
  int t = bid & 63;
  int k0 = (t >> 2) << 6;
  int m0 = (t & 3) << 6;
  int tt = threadIdx.x;
  {
    int r = tt >> 2;
    int cg = (tt & 3) << 4;
    const float* src = hg + (((size_t)b * NN + k0 + r) * MM + m0 + cg);
#pragma unroll
    for (int i = 0; i < 4; ++i) {
      float4 v = reinterpret_cast<const float4*>(src)[i];
      tile[r][cg + i * 4 + 0] = f2bf(v.x);
      tile[r][cg + i * 4 + 1] = f2bf(v.y);
      tile[r][cg + i * 4 + 2] = f2bf(v.z);
      tile[r][cg + i * 4 + 3] = f2bf(v.w);
    }
  }
  __syncthreads();
  {
    int mr = tt >> 2;
    int kc = (tt & 3) << 4;
    alignas(16) unsigned short tmp[16];
#pragma unroll
    for (int i = 0; i < 16; ++i) tmp[i] = tile[kc + i][mr];
    unsigned short* dst = hTg + (((size_t)b * MM + m0 + mr) * NN + k0 + kc);
    *reinterpret_cast<u16x8*>(dst)     = *reinterpret_cast<u16x8*>(tmp);
    *reinterpret_cast<u16x8*>(dst + 8) = *reinterpret_cast<u16x8*>(tmp + 8);
  }
}

// ------------- W transposes -------------
__global__ __launch_bounds__(256)
void k_transpose_w(const float* __restrict__ W1, const float* __restrict__ W2,
                   unsigned short* __restrict__ W1T, unsigned short* __restrict__ W2T) {
  int idx = blockIdx.x * 256 + threadIdx.x;
  if (idx < MM * HH) {
    int hc = idx >> 8;
    int m  = idx & 255;
    W1T[idx] = f2bf(W1[m * HH + hc]);
  } else {
    int j = idx - MM * HH;
    int m  = j >> 7;
    int hd = j & 127;
    W2T[j] = f2bf(W2[hd * MM + m]);
  }
}

// ---------------- fused main ----------------
// 256 blocks x 512 threads (8 waves 2x4). Block tile 128 rows x 256 cols.
// Phase 1: A fp32 [128][64] and hT bf16 [256][64] staged via global_load_lds,
// double-buffered; 2 raw barriers/step; counted vmcnt(8) keeps next step's
// loads in flight across the barrier. A converted to bf16 + rowmax during
// consume (fp32-exact).
// LDS: A0[0,32K) A1[32K,64K) H0[64K,96K) H1[96K,128K)
// phase2 alias: Kld[0,64K), Cld[64K,96K).
#define ABUF(x) ((x) * 32768)
#define HBUF(x) (65536 + (x) * 32768)
#define KLD 0
#define CLD 65536

#define PIPE_BARRIER() do { \
  asm volatile("s_waitcnt lgkmcnt(0)" ::: "memory"); \
  __builtin_amdgcn_s_barrier(); } while (0)

__global__ __launch_bounds__(512, 1)
void k_fused(const float* __restrict__ Ag, const float* __restrict__ hg,
             const unsigned short* __restrict__ hTg,
             const unsigned short* __restrict__ W1Tg,
             const unsigned short* __restrict__ W2Tg,
             const float* __restrict__ b1g, const float* __restrict__ b2g,
             float* __restrict__ outg) {
  __shared__ __align__(16) char smem[131072];
  __shared__ float smax[128];

  const int tid  = threadIdx.x;
  const int lane = tid & 63;
  const int wid  = tid >> 6;       // 0..7
  const int wr   = wid >> 2;       // 0..1 (row half)
  const int wc   = wid & 3;        // 0..3 (col quarter)
  const int l15  = lane & 15;
  const int lg   = lane >> 4;      // 0..3

  const int bid = blockIdx.x;
  const int b   = bid & 31;        // same-batch blocks share bid%8 -> same XCD
  const int r0  = (bid >> 5) << 7; // 8 row-blocks of 128

  const float* Ab = Ag + ((size_t)b * NN + r0) * NN;
  const unsigned short* hTb = hTg + (size_t)b * MM * NN;

  // ---- staging source pointers (inverse-swizzled so LDS dest is linear) ----
  const float* baseA[4];
  const unsigned short* baseH[4];
#pragma unroll
  for (int i = 0; i < 4; ++i) {
    int c = i * 512 + tid;           // A chunk: 16B of fp32, [128 rows][16 chunks]
    int row = c >> 4, cic = c & 15;
    baseA[i] = Ab + (size_t)row * NN + ((cic ^ ((row & 7) << 1)) << 2);
  }
#pragma unroll
  for (int i = 0; i < 4; ++i) {
    int c = i * 512 + tid;           // H chunk: 16B of bf16, [256 cols][8 chunks]
    int col = c >> 3, cic = c & 7;
    baseH[i] = hTb + (size_t)col * NN + ((cic ^ (col & 7)) << 3);
  }
  const int ldsW = wid << 10;        // wave-uniform chunk base (64 lanes x 16B)

#define STAGE(K0, AB, HB)                                                   \
  do {                                                                      \
    _Pragma("unroll")                                                       \
    for (int i = 0; i < 4; ++i)                                             \
      gl_lds16(baseA[i] + (K0), smem + (AB) + ldsW + i * 8192);             \
    _Pragma("unroll")                                                       \
    for (int i = 0; i < 4; ++i)                                             \
      gl_lds16(baseH[i] + (K0), smem + (HB) + ldsW + i * 8192);             \
  } while (0)

  f32x4 acc[4][4];
#pragma unroll
  for (int m = 0; m < 4; ++m)
#pragma unroll
    for (int n = 0; n < 4; ++n) acc[m][n] = f32x4{0.f, 0.f, 0.f, 0.f};
  float pm[4] = {-1e30f, -1e30f, -1e30f, -1e30f};

#define CONSUME(AB, HB)                                                     \
  do {                                                                      \
    _Pragma("unroll")                                                       \
    for (int kk = 0; kk < 2; ++kk) {                                        \
      bf16x8 af[4], bh[4];                                                  \
      _Pragma("unroll")                                                     \
      for (int m = 0; m < 4; ++m) {                                         \
        int row = (wr << 6) + (m << 4) + l15;                               \
        int boff = (AB) + row * 256 +                                       \
                   (((kk << 7) + (lg << 5)) ^ ((row & 7) << 5));            \
        float4 lo = *reinterpret_cast<const float4*>(smem + boff);          \
        float4 hi = *reinterpret_cast<const float4*>(smem + boff + 16);     \
        pm[m] = fmaxf(pm[m],                                                \
            fmaxf(fmaxf(fmaxf(lo.x, lo.y), fmaxf(lo.z, lo.w)),              \
                  fmaxf(fmaxf(hi.x, hi.y), fmaxf(hi.z, hi.w))));            \
        uint4 q = make_uint4(pack2(lo.x, lo.y), pack2(lo.z, lo.w),          \
                             pack2(hi.x, hi.y), pack2(hi.z, hi.w));         \
        af[m] = *reinterpret_cast<bf16x8*>(&q);                             \
      }                                                                     \
      _Pragma("unroll")                                                     \
      for (int n = 0; n < 4; ++n) {                                         \
        int col = (wc << 6) + (n << 4) + l15;                               \
        bh[n] = *reinterpret_cast<const bf16x8*>(smem + (HB) + col * 128 +  \
                 (((kk << 6) + (lg << 4)) ^ ((col & 7) << 4)));             \
      }                                                                     \
      _Pragma("unroll")                                                     \
      for (int m = 0; m < 4; ++m)                                           \
        _Pragma("unroll")                                                   \
        for (int n = 0; n < 4; ++n)                                         \
          acc[m][n] = __builtin_amdgcn_mfma_f32_16x16x32_bf16(af[m], bh[n], \
                                                              acc[m][n], 0, 0, 0); \
    }                                                                       \
  } while (0)

  // ---- prologue ----
  STAGE(0, ABUF(0), HBUF(0));

  // ---- phase 1: 16 K-steps of 64 ----
#pragma unroll
  for (int t = 0; t < 16; ++t) {
    __builtin_amdgcn_s_barrier();            // B1: prev step's readers retired
    if (t < 15) STAGE((t + 1) * 64, ABUF((t + 1) & 1), HBUF((t + 1) & 1));
    if (t < 15) asm volatile("s_waitcnt vmcnt(8)" ::: "memory");
    else        asm volatile("s_waitcnt vmcnt(0)" ::: "memory");
    __builtin_amdgcn_s_barrier();            // B2: all waves' step-t data in LDS
    if ((t & 1) == 0) CONSUME(ABUF(0), HBUF(0));
    else              CONSUME(ABUF(1), HBUF(1));
  }

  // ---- rowmax finalize: lanes lg=0..3 hold disjoint k-slices of each row ----
#pragma unroll
  for (int m = 0; m < 4; ++m) {
    float v = pm[m];
    v = fmaxf(v, __shfl_xor(v, 16));
    v = fmaxf(v, __shfl_xor(v, 32));
    if (wc == 0 && lg == 0) smax[(wr << 6) + (m << 4) + l15] = v;
  }
  PIPE_BARRIER();  // phase-1 LDS fully retired before aliasing

  // ---- write k tile (/3, bf16) -> Kld [128][512B] XOR ----
  {
    const float inv3 = 1.0f / 3.0f;
#pragma unroll
    for (int m = 0; m < 4; ++m)
#pragma unroll
      for (int n = 0; n < 4; ++n) {
        int col = (wc << 6) + (n << 4) + l15;
#pragma unroll
        for (int j = 0; j < 4; ++j) {
          int row = (wr << 6) + (m << 4) + (lg << 2) + j;
          *reinterpret_cast<unsigned short*>(smem + KLD + row * 512 +
                                             ((col * 2) ^ ((row & 7) << 4))) =
              f2bf(acc[m][n][j] * inv3);
        }
      }
  }
  PIPE_BARRIER();

  // ---- GEMM1: y[128][128] = k @ W1 (W1T fragments straight from L2) ----
  f32x4 acc1[4][2];
#pragma unroll
  for (int m = 0; m < 4; ++m)
#pragma unroll
    for (int n = 0; n < 2; ++n) acc1[m][n] = f32x4{0.f, 0.f, 0.f, 0.f};
  const int wcol1 = wc << 5;  // 0,32,64,96
#pragma unroll
  for (int kq = 0; kq < 8; ++kq) {
    bf16x8 af[4], bw[2];
#pragma unroll
    for (int m = 0; m < 4; ++m) {
      int row = (wr << 6) + (m << 4) + l15;
      af[m] = *reinterpret_cast<const bf16x8*>(smem + KLD + row * 512 +
              (((kq * 32 + (lg << 3)) * 2) ^ ((row & 7) << 4)));
    }
#pragma unroll
    for (int n = 0; n < 2; ++n) {
      int col = wcol1 + (n << 4) + l15;
      bw[n] = *reinterpret_cast<const bf16x8*>(W1Tg + (size_t)col * 256 +
                                               kq * 32 + (lg << 3));
    }
#pragma unroll
    for (int m = 0; m < 4; ++m)
#pragma unroll
      for (int n = 0; n < 2; ++n)
        acc1[m][n] = __builtin_amdgcn_mfma_f32_16x16x32_bf16(af[m], bw[n], acc1[m][n], 0, 0, 0);
  }

  // ---- c = relu(y+b1) -> Cld [128][256B] XOR (disjoint from Kld) ----
  {
#pragma unroll
    for (int n = 0; n < 2; ++n) {
      int col = wcol1 + (n << 4) + l15;
      float bias = b1g[col];
#pragma unroll
      for (int m = 0; m < 4; ++m)
#pragma unroll
        for (int j = 0; j < 4; ++j) {
          int row = (wr << 6) + (m << 4) + (lg << 2) + j;
          float v = fmaxf(acc1[m][n][j] + bias, 0.f);
          *reinterpret_cast<unsigned short*>(smem + CLD + row * 256 +
                                             ((col * 2) ^ ((row & 7) << 4))) = f2bf(v);
        }
    }
  }
  PIPE_BARRIER();

  // ---- GEMM2: out2[128][256] = c @ W2 (W2T fragments from L2) ----
  f32x4 acc2[4][4];
#pragma unroll
  for (int m = 0; m < 4; ++m)
#pragma unroll
    for (int n = 0; n < 4; ++n) acc2[m][n] = f32x4{0.f, 0.f, 0.f, 0.f};
#pragma unroll
  for (int kq = 0; kq < 4; ++kq) {
    bf16x8 af[4], bw[4];
#pragma unroll
    for (int m = 0; m < 4; ++m) {
      int row = (wr << 6) + (m << 4) + l15;
      af[m] = *reinterpret_cast<const bf16x8*>(smem + CLD + row * 256 +
              (((kq * 32 + (lg << 3)) * 2) ^ ((row & 7) << 4)));
    }
#pragma unroll
    for (int n = 0; n < 4; ++n) {
      int col = (wc << 6) + (n << 4) + l15;
      bw[n] = *reinterpret_cast<const bf16x8*>(W2Tg + (size_t)col * 128 +
                                               kq * 32 + (lg << 3));
    }
#pragma unroll
    for (int m = 0; m < 4; ++m)
#pragma unroll
      for (int n = 0; n < 4; ++n)
        acc2[m][n] = __builtin_amdgcn_mfma_f32_16x16x32_bf16(af[m], bw[n], acc2[m][n], 0, 0, 0);
  }

  // ---- epilogue: out = (out2+b2)*mask + h*(1-mask) ----
  {
#pragma unroll
    for (int n = 0; n < 4; ++n) {
      int col = (wc << 6) + (n << 4) + l15;
      float b2v = b2g[col];
#pragma unroll
      for (int m = 0; m < 4; ++m)
#pragma unroll
        for (int j = 0; j < 4; ++j) {
          int row = (wr << 6) + (m << 4) + (lg << 2) + j;
          float kv = acc2[m][n][j] + b2v;
          float mask = smax[row];
          size_t gidx = ((size_t)b * NN + r0 + row) * MM + col;
          float hv = hg[gidx];
          outg[gidx] = kv * mask + hv * (1.f - mask);
        }
    }
  }
#undef CONSUME
#undef STAGE
}

extern "C" void kernel_launch(void* const* d_in, const int* in_sizes, int n_in,
                              void* d_out, int out_size, void* d_ws, size_t ws_size,
                              hipStream_t stream) {
  (void)in_sizes; (void)n_in; (void)out_size; (void)ws_size;
  const float* A  = (const float*)d_in[0];
  const float* h  = (const float*)d_in[1];
  const float* W1 = (const float*)d_in[2];
  const float* b1 = (const float*)d_in[3];
  const float* W2 = (const float*)d_in[4];
  const float* b2 = (const float*)d_in[5];
  float* out = (float*)d_out;

  unsigned short* hT  = (unsigned short*)d_ws;
  unsigned short* W1T = (unsigned short*)((char*)d_ws + (size_t)BB * MM * NN * 2);
  unsigned short* W2T = W1T + MM * HH;

  k_transpose_h<<<BB * 64, 256, 0, stream>>>(h, hT);
  k_transpose_w<<<256, 256, 0, stream>>>(W1, W2, W1T, W2T);
  k_fused<<<BB * 8, 512, 0, stream>>>(A, h, hT, W1T, W2T, b1, b2, out);
}